// Round 8
// baseline (512.492 us; speedup 1.0000x reference)
//
#include <hip/hip_runtime.h>
#include <hip/hip_cooperative_groups.h>
#include <hip/hip_bf16.h>
#include <cstdint>
#include <cstddef>

namespace cg = cooperative_groups;

typedef __hip_bfloat16 bf16;
typedef __attribute__((ext_vector_type(8))) short short8;
typedef __attribute__((ext_vector_type(4))) short short4v;
typedef __attribute__((ext_vector_type(4))) float floatx4;

// Problem dims (all tensors float32; gates staged bf16 in LDS only)
#define BB 8
#define SS 4096
#define DIN 256
#define DH 512
#define NCH 256
#define CHUNK 16        // 8 chunks of 16 rows per 128-row m-tile

__device__ __forceinline__ float sh2f(short v) {
    unsigned int u = ((unsigned int)(unsigned short)v) << 16;
    float f; __builtin_memcpy(&f, &u, 4); return f;
}
__device__ __forceinline__ float frcp(float x) { return __builtin_amdgcn_rcpf(x); }
__device__ __forceinline__ short f2sh(float a) {
    bf16 bv = __float2bfloat16(a);
    short sv; __builtin_memcpy(&sv, &bv, 2); return sv;
}

__device__ __forceinline__ void load16_lds(const bf16* g, short* l)
{
    __builtin_amdgcn_global_load_lds(
        (const __attribute__((address_space(1))) unsigned int*)g,
        (__attribute__((address_space(3))) unsigned int*)l,
        16, 0, 0);
}

// ---------------- r5-proven GEMM tile body (73 us core) ----------------------
// MODE 0: GEMM + act(i,f,z) -> chunk carries to Aa/Bca/Bna.
// MODE 1: GEMM + act(all)  -> read chunk-start state from Aa/Bca, emit h.
template<int MODE>
__device__ __forceinline__ void gemm_tile(
    short* __restrict__ smem, int logical, int nb,
    const bf16* __restrict__ Xb, const bf16* __restrict__ Wt,
    const float* __restrict__ bi, const float* __restrict__ bfv,
    const float* __restrict__ bo, const float* __restrict__ bz,
    float* __restrict__ Aa, float* __restrict__ Bca, float* __restrict__ Bna,
    float* __restrict__ out)
{
    const int y  = logical & 15;
    const int gm = logical >> 4;          // pass-local m-tile (batch*32 + mt)
    const int m0 = gm * 128;
    const int n0 = y * 128;

    const int tid  = threadIdx.x;
    const int wave = tid >> 6, lane = tid & 63;
    const int wm   = (wave >> 1) * 64, wn = (wave & 1) * 64;
    const int l15  = lane & 15;
    const int q    = lane >> 4;

    floatx4 acc[4][4];
#pragma unroll
    for (int i = 0; i < 4; i++)
#pragma unroll
        for (int j = 0; j < 4; j++) acc[i][j] = (floatx4){0.f, 0.f, 0.f, 0.f};

    const int r_ld = tid >> 2;
    const int c_ld = tid & 3;
    const bf16* agp0 = Xb + (size_t)(m0 + r_ld) * DIN + c_ld * 8;
    const bf16* agp1 = Xb + (size_t)(m0 + 64 + r_ld) * DIN + c_ld * 8;
    const bf16* bgp0 = Wt + (size_t)(n0 + r_ld) * DIN + c_ld * 8;
    const bf16* bgp1 = Wt + (size_t)(n0 + 64 + r_ld) * DIN + c_ld * 8;

    // protect previous tile's smem readers before overwriting buffers
    __syncthreads();

#define STAGE(K0, BUF)                                            \
    do {                                                          \
        short* A_ = smem + (BUF) * 8192;                          \
        short* B_ = A_ + 4096;                                    \
        load16_lds(agp0 + (K0), &A_[tid * 8]);                    \
        load16_lds(agp1 + (K0), &A_[2048 + tid * 8]);             \
        load16_lds(bgp0 + (K0), &B_[tid * 8]);                    \
        load16_lds(bgp1 + (K0), &B_[2048 + tid * 8]);             \
    } while (0)

    STAGE(0, 0);
    asm volatile("s_waitcnt vmcnt(0)" ::: "memory");
    __builtin_amdgcn_s_barrier();

#pragma unroll
    for (int k = 0; k < 8; k++) {
        const int cur = k & 1;
        if (k < 7) STAGE((k + 1) * 32, cur ^ 1);
        const short* A = smem + cur * 8192;
        const short* B = A + 4096;
        short8 af[4], bfr[4];
#pragma unroll
        for (int ti = 0; ti < 4; ti++)
            af[ti] = *(const short8*)&A[(wm + ti * 16 + l15) * 32 + q * 8];
#pragma unroll
        for (int tj = 0; tj < 4; tj++)
            bfr[tj] = *(const short8*)&B[(wn + tj * 16 + l15) * 32 + q * 8];
#pragma unroll
        for (int ti = 0; ti < 4; ti++)
#pragma unroll
            for (int tj = 0; tj < 4; tj++)
                acc[ti][tj] = __builtin_amdgcn_mfma_f32_16x16x32_bf16(
                    af[ti], bfr[tj], acc[ti][tj], 0, 0, 0);
        // drain + compiler memory fence (rule #18: s_barrier alone is NoMem)
        asm volatile("s_waitcnt vmcnt(0) lgkmcnt(0)" ::: "memory");
        __builtin_amdgcn_s_barrier();
    }
#undef STAGE

    // -------- epilogue: bias + activation -> bf16 -> LDS C-tile [m][132] ----
#pragma unroll
    for (int ti = 0; ti < 4; ti++) {
        const int mrow = wm + ti * 16 + q * 4;       // tile-local row
#pragma unroll
        for (int tj = 0; tj < 4; tj++) {
            const int cb = wn + tj * 16;             // wave-uniform col base
            const int g  = cb >> 5;                  // gate 0..3 (uniform)
            if (MODE == 0 && g == 2) continue;       // o unused in carry pass
            const int c  = cb + l15;                 // tile-local col
            const float* bp = (g == 0) ? bi : (g == 1) ? bfv
                            : (g == 2) ? bo : bz;
            const float bsv = bp[y * 32 + (c & 31)];
#pragma unroll
            for (int r = 0; r < 4; r++) {
                const float v = acc[ti][tj][r] + bsv;
                float a;
                if (g == 0 || g == 1) {
                    a = __expf(fminf(fmaxf(v, -20.f), 0.f));     // exp(clip)
                } else if (g == 2) {
                    a = frcp(1.f + __expf(-v));                  // sigmoid
                } else {
                    a = 1.f - 2.f * frcp(__expf(2.f * v) + 1.f); // tanh
                }
                smem[(mrow + r) * 132 + c] = f2sh(a);
            }
        }
    }
    __syncthreads();

    const int bidx = m0 / SS;                        // pass-local batch
    const int hh   = tid & 31;
    const int ch   = tid >> 5;                       // chunk (16 rows) in tile
    const int ch_g = ((m0 % SS) >> 4) + ch;          // batch-local chunk
    const size_t cidx = (size_t)(ch_g * nb + bidx) * DH + y * 32 + hh;
    const short* base = &smem[(ch * CHUNK) * 132];

    if (MODE == 0) {
        // ---- fused chunk-carry: 256 chains (8 chunks x 32 h), f32 scan ----
        float A = 1.f, Bc = 0.f, Bn = 0.f;
#pragma unroll
        for (int s = 0; s < CHUNK; s++) {
            const short* rp = base + s * 132;
            const float iv = sh2f(rp[hh]);
            const float f  = sh2f(rp[32 + hh]);
            const float zv = sh2f(rp[96 + hh]);
            Bc = fmaf(f, Bc, iv * zv);
            Bn = fmaf(f, Bn, iv);
            A *= f;
        }
        Aa[cidx] = A; Bca[cidx] = Bc; Bna[cidx] = Bn;
    } else {
        // ---- scan + emit: replay chunk with true init, h -> out (f32) -----
        float c = Aa[cidx];       // c-before-chunk (post scan phase)
        float n = Bca[cidx];      // n-before-chunk
        float* orow = out + (size_t)(m0 + ch * CHUNK) * DH + y * 32 + hh;
#pragma unroll
        for (int s = 0; s < CHUNK; s++) {
            const short* rp = base + s * 132;
            const float iv = sh2f(rp[hh]);
            const float f  = sh2f(rp[32 + hh]);
            const float ov = sh2f(rp[64 + hh]);
            const float zv = sh2f(rp[96 + hh]);
            c = fmaf(f, c, iv * zv);
            n = fmaf(f, n, iv);
            orow[(size_t)s * DH] = ov * c * frcp(n + 1e-6f);
        }
    }
}

// ---------------- single cooperative kernel: 4 phases, 3 grid syncs ----------
// phase 0: transpose W (gate-interleaved) + convert x -> bf16
// phase 1: GEMM + chunk carries          (r5 mode 0, grid-stride over tiles)
// phase 2: two-level scan over carries   (in-place; Aa:=c-start, Bca:=n-start)
// phase 3: GEMM + scan-replay + emit h   (r5 mode 1)
extern "C" __global__ void __launch_bounds__(256) fused_all(
    const float* __restrict__ Wi, const float* __restrict__ Wf,
    const float* __restrict__ Wo, const float* __restrict__ Wz,
    const float* __restrict__ X,
    bf16* __restrict__ Wt, bf16* __restrict__ Xb,
    const float* __restrict__ bi, const float* __restrict__ bfv,
    const float* __restrict__ bo, const float* __restrict__ bz,
    float* __restrict__ Aa, float* __restrict__ Bca, float* __restrict__ Bna,
    float* __restrict__ out, int nb, int doTrans)
{
    __shared__ __align__(16) short smem[128 * 132];   // 33792 B
    cg::grid_group grid = cg::this_grid();

    const int tid = threadIdx.x;
    const int bid = blockIdx.x;
    const int G   = gridDim.x;
    const int gt  = bid * 256 + tid;
    const int NTH = G * 256;

    // ---------------- phase 0: prep ----------------
    if (doTrans) {
        for (int o = gt; o < 2048 * 256; o += NTH) {
            int r = o >> 8, k = o & 255;
            int y = r >> 7, c = r & 127;
            int g = c >> 5, h = y * 32 + (c & 31);
            const float* W = (g == 0) ? Wi : (g == 1) ? Wf : (g == 2) ? Wo : Wz;
            Wt[o] = __float2bfloat16(W[(size_t)k * DH + h]);
        }
    }
    {
        const int nvec = nb * SS * DIN / 4;
        for (int i = gt; i < nvec; i += NTH) {
            float4 v = ((const float4*)X)[i];
            bf16 o4[4] = {__float2bfloat16(v.x), __float2bfloat16(v.y),
                          __float2bfloat16(v.z), __float2bfloat16(v.w)};
            ((short4v*)Xb)[i] = *(const short4v*)o4;
        }
    }
    __threadfence();
    grid.sync();

    // ---------------- phase 1: GEMM + carries ----------------
    const int NT  = nb * 512;
    const int cpx = NT >> 3;
    for (int d = bid; d < NT; d += G) {
        const int logical = ((d & 7) * cpx) + (d >> 3);   // XCD-contiguous
        gemm_tile<0>(smem, logical, nb, Xb, Wt, bi, bfv, bo, bz,
                     Aa, Bca, Bna, out);
    }
    __threadfence();
    grid.sync();

    // ---------------- phase 2: two-level scan (r5-proven) ----------------
    if (bid < nb * 8) {
        float* sA  = (float*)smem;          // [4][64] carved from smem
        float* sBc = sA + 256;
        float* sBn = sBc + 256;
        const int l  = tid & 63;
        const int t  = bid * 64 + l;        // chain id (b*512+h)
        const int s  = tid >> 6;            // segment 0..3
        const int stride = nb * DH;
        const int SEG = NCH / 4;            // 64

        float A = 1.f, Bc = 0.f, Bn = 0.f;
        for (int k = 0; k < SEG; k++) {
            const size_t cidx = (size_t)(s * SEG + k) * stride + t;
            const float a  = Aa[cidx];
            const float bc = Bca[cidx];
            const float bn = Bna[cidx];
            Bc = fmaf(a, Bc, bc);
            Bn = fmaf(a, Bn, bn);
            A *= a;
        }
        sA[s * 64 + l] = A; sBc[s * 64 + l] = Bc; sBn[s * 64 + l] = Bn;
        __syncthreads();

        float c = 0.f, n = 1.f;
#pragma unroll
        for (int s2 = 0; s2 < 3; s2++) {
            if (s2 < s) {
                const float a  = sA[s2 * 64 + l];
                const float nc = fmaf(a, c, sBc[s2 * 64 + l]);
                n = fmaf(a, n, sBn[s2 * 64 + l]);
                c = nc;
            }
        }
        for (int k = 0; k < SEG; k++) {
            const size_t cidx = (size_t)(s * SEG + k) * stride + t;
            const float a  = Aa[cidx];
            const float bc = Bca[cidx];
            const float bn = Bna[cidx];
            Aa[cidx] = c; Bca[cidx] = n;    // state BEFORE chunk
            const float nc = fmaf(a, c, bc);
            n = fmaf(a, n, bn);
            c = nc;
        }
    }
    __threadfence();
    grid.sync();

    // ---------------- phase 3: GEMM + emit ----------------
    for (int d = bid; d < NT; d += G) {
        const int logical = ((d & 7) * cpx) + (d >> 3);
        gemm_tile<1>(smem, logical, nb, Xb, Wt, bi, bfv, bo, bz,
                     Aa, Bca, Bna, out);
    }
}

// ---------------- launch -----------------------------------------------------
extern "C" void kernel_launch(void* const* d_in, const int* in_sizes, int n_in,
                              void* d_out, int out_size, void* d_ws, size_t ws_size,
                              hipStream_t stream)
{
    const float* x   = (const float*)d_in[0];
    const float* Wi  = (const float*)d_in[1];
    const float* bi  = (const float*)d_in[2];
    const float* Wf  = (const float*)d_in[3];
    const float* bfv = (const float*)d_in[4];
    const float* Wo  = (const float*)d_in[5];
    const float* bo  = (const float*)d_in[6];
    const float* Wz  = (const float*)d_in[7];
    const float* bz  = (const float*)d_in[8];
    float* out = (float*)d_out;

    // ws-adaptive: nb batches per pass (Wt + Xb + carry arrays only)
    int nb = BB;
    while (nb > 1) {
        size_t need = (1u << 20)                         // Wt
                    + (size_t)nb * SS * DIN * 2          // Xb
                    + 3 * (size_t)NCH * nb * DH * 4;     // Aa,Bca,Bna
        if (need <= ws_size) break;
        nb >>= 1;
    }

    bf16* Wt = (bf16*)d_ws;
    bf16* Xb = (bf16*)((char*)d_ws + (1u << 20));
    float* Aa  = (float*)(Xb + (size_t)nb * SS * DIN);
    float* Bca = Aa  + (size_t)NCH * nb * DH;
    float* Bna = Bca + (size_t)NCH * nb * DH;

    // co-residency-safe grid for cooperative launch (cached query, no stream op)
    static int maxB = -1;
    if (maxB < 0) {
        if (hipOccupancyMaxActiveBlocksPerMultiprocessor(
                &maxB, (const void*)fused_all, 256, 0) != hipSuccess || maxB < 1)
            maxB = 1;
        if (maxB > 8) maxB = 8;
    }
    const int NUM_CU = 256;                // MI355X

    for (int b0 = 0; b0 < BB; b0 += nb) {
        const float* Xsrc = x   + (size_t)b0 * SS * DIN;
        float*       Ob   = out + (size_t)b0 * SS * DH;
        int G = maxB * NUM_CU;
        if (G > nb * 512) G = nb * 512;
        int nbArg = nb;
        int doT = (b0 == 0) ? 1 : 0;
        void* args[] = {
            (void*)&Wi, (void*)&Wf, (void*)&Wo, (void*)&Wz,
            (void*)&Xsrc, (void*)&Wt, (void*)&Xb,
            (void*)&bi, (void*)&bfv, (void*)&bo, (void*)&bz,
            (void*)&Aa, (void*)&Bca, (void*)&Bna,
            (void*)&Ob, (void*)&nbArg, (void*)&doT
        };
        hipLaunchCooperativeKernel((const void*)fused_all,
                                   dim3(G), dim3(256), args, 0, stream);
    }
}

// Round 9
// 228.391 us; speedup vs baseline: 2.2439x; 2.2439x over previous
//
#include <hip/hip_runtime.h>
#include <hip/hip_bf16.h>
#include <cstdint>
#include <cstddef>

typedef __hip_bfloat16 bf16;
typedef __attribute__((ext_vector_type(8))) short short8;
typedef __attribute__((ext_vector_type(4))) short short4v;
typedef __attribute__((ext_vector_type(4))) float floatx4;

// Problem dims (all tensors float32; gates staged bf16)
#define BB 8
#define SS 4096
#define DIN 256
#define DH 512
#define NCH 256
#define CHUNK 16       // NCH*CHUNK == SS

__device__ __forceinline__ float sh2f(short v) {
    unsigned int u = ((unsigned int)(unsigned short)v) << 16;
    float f; __builtin_memcpy(&f, &u, 4); return f;
}
__device__ __forceinline__ float frcp(float x) { return __builtin_amdgcn_rcpf(x); }
__device__ __forceinline__ short f2sh(float a) {
    bf16 bv = __float2bfloat16(a);
    short sv; __builtin_memcpy(&sv, &bv, 2); return sv;
}

// ---------------- kernel 0: fused prep (transpose_w + convert_x) -------------
// bx < tblk : W (f32 [256][512] x4) -> Wt (bf16 [2048][256]), gate-interleaved
//             N: row r = y*128 + g*32 + hh  ->  gate g, h = y*32 + hh.
// else      : x tile f32 -> bf16 (4 elems/thread)
__global__ __launch_bounds__(256) void prep(
    const float* __restrict__ Wi, const float* __restrict__ Wf,
    const float* __restrict__ Wo, const float* __restrict__ Wz,
    bf16* __restrict__ Wt,
    const float* __restrict__ X, bf16* __restrict__ Xb, int tblk)
{
    const int bx = blockIdx.x;
    const int tid = threadIdx.x;
    if (bx < tblk) {
        int o = bx * 256 + tid;               // 0..524287
        int r = o >> 8;                       // interleaved n index 0..2047
        int k = o & 255;
        int y = r >> 7;                       // h-group 0..15
        int c = r & 127;
        int g = c >> 5;                       // gate 0..3
        int h = y * 32 + (c & 31);            // 0..511
        const float* W = (g == 0) ? Wi : (g == 1) ? Wf : (g == 2) ? Wo : Wz;
        Wt[o] = __float2bfloat16(W[(size_t)k * DH + h]);
    } else {
        const int idx = (bx - tblk) * 256 + tid;
        float4 v = ((const float4*)X)[idx];
        bf16 o4[4] = {__float2bfloat16(v.x), __float2bfloat16(v.y),
                      __float2bfloat16(v.z), __float2bfloat16(v.w)};
        ((short4v*)Xb)[idx] = *(const short4v*)o4;
    }
}

// ---------------- kernel 1: MFMA GEMM + bias + act + gates + chunk carries ---
__device__ __forceinline__ void load16_lds(const bf16* g, short* l)
{
    __builtin_amdgcn_global_load_lds(
        (const __attribute__((address_space(1))) unsigned int*)g,
        (__attribute__((address_space(3))) unsigned int*)l,
        16, 0, 0);
}

// 1D grid nb*512; XCD-contiguous swizzle (r4-proven: FETCH 68->16 MB): each
// XCD owns a contiguous logical range; consecutive logicals are y-fast so the
// 16 n-sharers of one A-panel run near-simultaneously on one L2.
__global__ __launch_bounds__(256) void gemm_mfma(
    const bf16* __restrict__ Xb, const bf16* __restrict__ Wt,
    const float* __restrict__ bi, const float* __restrict__ bfv,
    const float* __restrict__ bo, const float* __restrict__ bz,
    bf16* __restrict__ Pi, bf16* __restrict__ Pf,
    bf16* __restrict__ Po, bf16* __restrict__ Pz,
    float* __restrict__ Aa, float* __restrict__ Bca, float* __restrict__ Bna,
    int nb)
{
    // K-loop: 2 x 16 KB staging double-buffer; epilogue reuses the whole
    // buffer as the 128x132(pad) bf16 C-tile (33792 B -> 4 blocks/CU).
    __shared__ __align__(16) short smem[128 * 132];

    const int cpx = gridDim.x >> 3;
    const int logical = ((int)blockIdx.x & 7) * cpx + ((int)blockIdx.x >> 3);
    const int y  = logical & 15;
    const int m0 = (logical >> 4) * 128;
    const int n0 = y * 128;

    const int tid  = threadIdx.x;
    const int wave = tid >> 6, lane = tid & 63;
    const int wm   = (wave >> 1) * 64, wn = (wave & 1) * 64;
    const int l15  = lane & 15;
    const int q    = lane >> 4;

    floatx4 acc[4][4];
#pragma unroll
    for (int i = 0; i < 4; i++)
#pragma unroll
        for (int j = 0; j < 4; j++) acc[i][j] = (floatx4){0.f, 0.f, 0.f, 0.f};

    const int r_ld = tid >> 2;
    const int c_ld = tid & 3;
    const bf16* agp0 = Xb + (size_t)(m0 + r_ld) * DIN + c_ld * 8;
    const bf16* agp1 = Xb + (size_t)(m0 + 64 + r_ld) * DIN + c_ld * 8;
    const bf16* bgp0 = Wt + (size_t)(n0 + r_ld) * DIN + c_ld * 8;
    const bf16* bgp1 = Wt + (size_t)(n0 + 64 + r_ld) * DIN + c_ld * 8;

    // Counted-vmcnt 2-buffer pipeline: at iter k stage(k+1) is issued first,
    // then vmcnt(4) waits ONLY for my 4 stage-k loads (stage-k+1 stays in
    // flight across this iteration's ds_read+MFMA). No sched_barrier, 32 KB
    // LDS (4 blocks/CU) — r4's regression co-factors removed.
    // FENCE DISCIPLINE (rule #18): every s_barrier is preceded by an asm with
    // a "memory" clobber so LDS writes can't hoist above it at compile time.
#define STAGE(K0, BUF)                                            \
    do {                                                          \
        short* A_ = smem + (BUF) * 8192;                          \
        short* B_ = A_ + 4096;                                    \
        load16_lds(agp0 + (K0), &A_[tid * 8]);                    \
        load16_lds(agp1 + (K0), &A_[2048 + tid * 8]);             \
        load16_lds(bgp0 + (K0), &B_[tid * 8]);                    \
        load16_lds(bgp1 + (K0), &B_[2048 + tid * 8]);             \
    } while (0)

    STAGE(0, 0);

#pragma unroll
    for (int k = 0; k < 8; k++) {
        const int cur = k & 1;
        if (k < 7) STAGE((k + 1) * 32, cur ^ 1);
        // wait: stage-k landed (4 outstanding allowed = stage-k+1 in flight)
        if (k < 7) asm volatile("s_waitcnt vmcnt(4)" ::: "memory");
        else       asm volatile("s_waitcnt vmcnt(0)" ::: "memory");
        __builtin_amdgcn_s_barrier();          // all waves' stage(k) landed

        const short* A = smem + cur * 8192;
        const short* B = A + 4096;
        short8 af[4], bfr[4];
#pragma unroll
        for (int ti = 0; ti < 4; ti++)
            af[ti] = *(const short8*)&A[(wm + ti * 16 + l15) * 32 + q * 8];
#pragma unroll
        for (int tj = 0; tj < 4; tj++)
            bfr[tj] = *(const short8*)&B[(wn + tj * 16 + l15) * 32 + q * 8];
#pragma unroll
        for (int ti = 0; ti < 4; ti++)
#pragma unroll
            for (int tj = 0; tj < 4; tj++)
                acc[ti][tj] = __builtin_amdgcn_mfma_f32_16x16x32_bf16(
                    af[ti], bfr[tj], acc[ti][tj], 0, 0, 0);
        // lgkm already drained by MFMA data deps (cheap); the "memory" clobber
        // keeps next iteration's STAGE below this barrier at compile time.
        asm volatile("s_waitcnt lgkmcnt(0)" ::: "memory");
        __builtin_amdgcn_s_barrier();          // buf cur free for overwrite
    }
#undef STAGE

    // -------- epilogue: bias + activation -> bf16 -> LDS C-tile [m][132] ----
#pragma unroll
    for (int ti = 0; ti < 4; ti++) {
        const int mrow = wm + ti * 16 + q * 4;       // tile-local row
#pragma unroll
        for (int tj = 0; tj < 4; tj++) {
            const int cb = wn + tj * 16;             // wave-uniform col base
            const int g  = cb >> 5;                  // gate 0..3 (uniform)
            const int c  = cb + l15;                 // tile-local col
            const float* bp = (g == 0) ? bi : (g == 1) ? bfv
                            : (g == 2) ? bo : bz;
            const float bsv = bp[y * 32 + (c & 31)];
#pragma unroll
            for (int r = 0; r < 4; r++) {
                const float v = acc[ti][tj][r] + bsv;
                float a;
                if (g == 0 || g == 1) {
                    a = __expf(fminf(fmaxf(v, -20.f), 0.f));     // exp(clip)
                } else if (g == 2) {
                    a = frcp(1.f + __expf(-v));                  // sigmoid
                } else {
                    a = 1.f - 2.f * frcp(__expf(2.f * v) + 1.f); // tanh
                }
                smem[(mrow + r) * 132 + c] = f2sh(a);
            }
        }
    }
    __syncthreads();

    const int bidx = m0 / SS;            // pass-local batch (SS % 128 == 0)

    // -------- coalesced copy-out: LDS -> gate planes, 8 B per lane ----------
    {
        const int cp  = (tid & 31) * 4;              // col base (4 cols, 1 gate)
        const int g2  = cp >> 5;
        const int hb  = y * 32 + (cp & 31);
        bf16* pl = ((g2 == 0) ? Pi : (g2 == 1) ? Pf : (g2 == 2) ? Po : Pz) + hb;
        const int r0 = tid >> 5;
#pragma unroll
        for (int t = 0; t < 16; t++) {
            const int row = t * 8 + r0;
            short4v v = *(const short4v*)&smem[row * 132 + cp];
            *(short4v*)(pl + (size_t)(m0 + row) * DH) = v;
        }
    }

    // -------- fused chunk-carry: 256 chains (8 chunks x 32 h), f32 scan -----
    {
        const int hh = tid & 31;
        const int ch = tid >> 5;                     // chunk (16 rows) in tile
        float A = 1.f, Bc = 0.f, Bn = 0.f;
        const short* base = &smem[(ch * CHUNK) * 132];
#pragma unroll
        for (int s = 0; s < CHUNK; s++) {
            const short* rp = base + s * 132;
            const float iv = sh2f(rp[hh]);
            const float f  = sh2f(rp[32 + hh]);
            const float zv = sh2f(rp[96 + hh]);
            Bc = fmaf(f, Bc, iv * zv);
            Bn = fmaf(f, Bn, iv);
            A *= f;
        }
        const int ch_g = ((m0 % SS) >> 4) + ch;      // batch-local chunk 0..255
        const int hgl  = y * 32 + hh;
        const size_t cidx = (size_t)(ch_g * nb + bidx) * DH + hgl;
        Aa[cidx] = A; Bca[cidx] = Bc; Bna[cidx] = Bn;
    }
}

// ---------------- kernel 2: two-level scan over chunk carries (in-place) -----
// After this kernel Aa holds c-before-chunk, Bca holds n-before-chunk.
// Block = 64 chains x 4 segments of 64 chunks. Serial length 64, not 256.
__global__ __launch_bounds__(256) void scan_chunks(
    float* __restrict__ Aa, float* __restrict__ Bca,
    const float* __restrict__ Bna, int nb)
{
    __shared__ float sA[4][64], sBc[4][64], sBn[4][64];
    const int tid = threadIdx.x;
    const int t   = blockIdx.x * 64 + (tid & 63);   // chain id (b*512+h)
    const int s   = tid >> 6;                        // segment 0..3
    const int stride = nb * DH;
    const int SEG = NCH / 4;                         // 64

    // level 1: compose the segment's affine map
    float A = 1.f, Bc = 0.f, Bn = 0.f;
    for (int k = 0; k < SEG; k++) {
        const size_t cidx = (size_t)(s * SEG + k) * stride + t;
        const float a  = Aa[cidx];
        const float bc = Bca[cidx];
        const float bn = Bna[cidx];
        Bc = fmaf(a, Bc, bc);
        Bn = fmaf(a, Bn, bn);
        A *= a;
    }
    sA[s][tid & 63] = A; sBc[s][tid & 63] = Bc; sBn[s][tid & 63] = Bn;
    __syncthreads();

    // level 2: segment-start state for my segment
    float c = 0.f, n = 1.f;
#pragma unroll
    for (int s2 = 0; s2 < 3; s2++) {
        if (s2 < s) {
            const float a  = sA[s2][tid & 63];
            const float nc = fmaf(a, c, sBc[s2][tid & 63]);
            n = fmaf(a, n, sBn[s2][tid & 63]);
            c = nc;
        }
    }

    // level 3: replay (L2-hot), write prefix state BEFORE each chunk
    for (int k = 0; k < SEG; k++) {
        const size_t cidx = (size_t)(s * SEG + k) * stride + t;
        const float a  = Aa[cidx];
        const float bc = Bca[cidx];
        const float bn = Bna[cidx];
        Aa[cidx] = c; Bca[cidx] = n;
        const float nc = fmaf(a, c, bc);
        n = fmaf(a, n, bn);
        c = nc;
    }
}

// ---------------- kernel 3: replay chunk with true init, emit h (f32) --------
// 2 chunks/block, 4 h/thread -> NCH/2 * nb = 1024 blocks (16 waves/CU).
__global__ __launch_bounds__(256) void scan_emit(
    const bf16* __restrict__ Pi, const bf16* __restrict__ Pf,
    const bf16* __restrict__ Po, const bf16* __restrict__ Pz,
    const float* __restrict__ Cs, const float* __restrict__ Ns,
    float* __restrict__ out, int nb)
{
    const int tid = threadIdx.x;
    const int ch  = blockIdx.x * 2 + (tid >> 7);
    const int b   = blockIdx.y;
    const int hg  = (tid & 127) * 4;
    const size_t base = ((size_t)(b * SS + ch * CHUNK)) * DH + hg;
    const size_t cidx = (size_t)(ch * nb + b) * DH + hg;

    float c[4], n[4];
    *(floatx4*)c = *(const floatx4*)(Cs + cidx);
    *(floatx4*)n = *(const floatx4*)(Ns + cidx);

#pragma unroll 4
    for (int s = 0; s < CHUNK; s++) {
        const size_t o = base + (size_t)s * DH;
        short4v i4 = *(const short4v*)(Pi + o);
        short4v f4 = *(const short4v*)(Pf + o);
        short4v o4 = *(const short4v*)(Po + o);
        short4v z4 = *(const short4v*)(Pz + o);
        float h[4];
#pragma unroll
        for (int j = 0; j < 4; j++) {
            const float f  = sh2f(f4[j]);
            const float iv = sh2f(i4[j]);
            const float ov = sh2f(o4[j]);
            const float zv = sh2f(z4[j]);
            c[j] = fmaf(f, c[j], iv * zv);
            n[j] = fmaf(f, n[j], iv);
            h[j] = ov * c[j] * frcp(n[j] + 1e-6f);
        }
        *(floatx4*)(out + o) = *(floatx4*)h;
    }
}

// ---------------- launch -----------------------------------------------------
extern "C" void kernel_launch(void* const* d_in, const int* in_sizes, int n_in,
                              void* d_out, int out_size, void* d_ws, size_t ws_size,
                              hipStream_t stream)
{
    const float* x   = (const float*)d_in[0];
    const float* Wi  = (const float*)d_in[1];
    const float* bi  = (const float*)d_in[2];
    const float* Wf  = (const float*)d_in[3];
    const float* bfv = (const float*)d_in[4];
    const float* Wo  = (const float*)d_in[5];
    const float* bo  = (const float*)d_in[6];
    const float* Wz  = (const float*)d_in[7];
    const float* bz  = (const float*)d_in[8];
    float* out = (float*)d_out;

    // ws-adaptive: nb batches per pass.
    int nb = BB;
    while (nb > 1) {
        size_t need = (1u << 20)                         // Wt
                    + (size_t)nb * SS * DIN * 2          // Xb
                    + 4 * (size_t)nb * SS * DH * 2       // Pi,Pf,Po,Pz
                    + 3 * (size_t)NCH * nb * DH * 4;     // Aa,Bca,Bna (in-place)
        if (need <= ws_size) break;
        nb >>= 1;
    }

    const size_t plane = (size_t)nb * SS * DH;
    bf16* Wt = (bf16*)d_ws;
    bf16* Xb = (bf16*)((char*)d_ws + (1u << 20));
    bf16* Pi = Xb + (size_t)nb * SS * DIN;
    bf16* Pf = Pi + plane;
    bf16* Po = Pf + plane;
    bf16* Pz = Po + plane;
    float* Aa  = (float*)(Pz + plane);
    float* Bca = Aa  + (size_t)NCH * nb * DH;
    float* Bna = Bca + (size_t)NCH * nb * DH;

    for (int b0 = 0; b0 < BB; b0 += nb) {
        const float* Xsrc = x   + (size_t)b0 * SS * DIN;
        float*       Ob   = out + (size_t)b0 * SS * DH;
        const int tblk = (b0 == 0) ? 2048 : 0;          // transpose only once
        prep<<<tblk + nb * 1024, 256, 0, stream>>>(
            Wi, Wf, Wo, Wz, Wt, Xsrc, Xb, tblk);
        gemm_mfma<<<nb * 512, 256, 0, stream>>>(
            Xb, Wt, bi, bfv, bo, bz, Pi, Pf, Po, Pz, Aa, Bca, Bna, nb);
        scan_chunks<<<nb * 8, 256, 0, stream>>>(Aa, Bca, Bna, nb);
        scan_emit<<<dim3(NCH / 2, nb), 256, 0, stream>>>(
            Pi, Pf, Po, Pz, Aa, Bca, Ob, nb);
    }
}